// Round 1
// baseline (147.190 us; speedup 1.0000x reference)
//
#include <hip/hip_runtime.h>
#include <math.h>

#define FDIM 256
#define NH 8
#define HD 32
#define NQ 4096
#define NKEY 4096
#define CAP 512
#define R2 9.0f

typedef _Float16 half8 __attribute__((ext_vector_type(8)));
typedef _Float16 half4v __attribute__((ext_vector_type(4)));
typedef float f32x4 __attribute__((ext_vector_type(4)));
typedef unsigned int u32x4 __attribute__((ext_vector_type(4)));
typedef unsigned short ushort_t;

// castbuf layout (f16 elements)
#define CB_CUR  0
#define CB_HIST 1048576
#define CB_WQ   2097152
#define CB_WK   2162688
#define CB_WV   2228224
#define CB_WO   2293760
#define CB_F4_TOTAL 589824  // total float4 groups (2359296 floats / 4)

// ---------------------------------------------------------------------------
// Non-temporal helpers: streaming data (Qh rows, nbr lists, Ob stores) must
// not evict the KV table, which we are deliberately keeping L2-resident.
// ---------------------------------------------------------------------------
__device__ __forceinline__ half8 nt_load_half8(const _Float16* p) {
    u32x4 u = __builtin_nontemporal_load((const u32x4*)p);
    union { u32x4 u; half8 h; } c; c.u = u; return c.h;
}
__device__ __forceinline__ void nt_store_half8(_Float16* p, half8 h) {
    union { u32x4 u; half8 h; } c; c.h = h;
    __builtin_nontemporal_store(c.u, (u32x4*)p);
}

// 64-cell morton id (4x4x4 cells of edge 4.0 over the 16^3 extent).
__device__ __forceinline__ int cell_id(float x, float y, float z) {
    int cx = (int)(x * 0.25f); cx = cx < 0 ? 0 : (cx > 3 ? 3 : cx);
    int cy = (int)(y * 0.25f); cy = cy < 0 ? 0 : (cy > 3 ? 3 : cy);
    int cz = (int)(z * 0.25f); cz = cz < 0 ? 0 : (cz > 3 ? 3 : cz);
    int m = 0;
#pragma unroll
    for (int b = 0; b < 2; ++b)
        m |= (((cx >> b) & 1) << (3 * b + 2)) |
             (((cy >> b) & 1) << (3 * b + 1)) |
             (((cz >> b) & 1) << (3 * b + 0));
    return m;  // morton: chunks of consecutive cells are spatially compact
}

// ---------------------------------------------------------------------------
// prep: blocks [0,1024) build the neighbor lists; blocks [1024,2048) cast all
// GEMM inputs fp32->fp16 (grid-stride); block 2048 does a single-block
// spatial counting sort of the queries (morton cell order). The sort's
// single-CU latency hides under the other 2048 blocks.
// ---------------------------------------------------------------------------
__global__ __launch_bounds__(256) void prep(const float* __restrict__ cur,
                                            const float* __restrict__ histf,
                                            const float* __restrict__ Wq,
                                            const float* __restrict__ Wk,
                                            const float* __restrict__ Wv,
                                            const float* __restrict__ Wo,
                                            _Float16* __restrict__ dst,
                                            const float* __restrict__ qc,
                                            const float* __restrict__ kc,
                                            ushort_t* __restrict__ nbr,
                                            int* __restrict__ cnt,
                                            ushort_t* __restrict__ order) {
    if (blockIdx.x < 1024) {
        // ---- neighbor build: exact reference fp32 op order (no contraction)
        const int q    = blockIdx.x * 4 + (threadIdx.x >> 6);
        const int lane = threadIdx.x & 63;
        const float qx = qc[q * 3 + 0];
        const float qy = qc[q * 3 + 1];
        const float qz = qc[q * 3 + 2];
        int base = 0;
        for (int k0 = 0; k0 < NKEY; k0 += 64) {
            const int k = k0 + lane;
            float dx = __fsub_rn(qx, kc[k * 3 + 0]);
            float dy = __fsub_rn(qy, kc[k * 3 + 1]);
            float dz = __fsub_rn(qz, kc[k * 3 + 2]);
            float d2 = __fadd_rn(__fadd_rn(__fmul_rn(dx, dx), __fmul_rn(dy, dy)),
                                 __fmul_rn(dz, dz));
            bool valid = (d2 <= R2);
            unsigned long long bal = __ballot(valid);
            if (valid) {
                int pos = base + __popcll(bal & ((1ull << lane) - 1ull));
                if (pos < CAP) nbr[(size_t)q * CAP + pos] = (ushort_t)k;
            }
            base += __popcll(bal);
        }
        if (lane == 0) cnt[q] = (base > CAP) ? CAP : base;
    } else if (blockIdx.x < 2048) {
        // ---- fp32 -> fp16 cast of feats + weights
        const int stride = 1024 * 256;
        for (int i4 = (blockIdx.x - 1024) * 256 + threadIdx.x; i4 < CB_F4_TOTAL;
             i4 += stride) {
            const float* src;
            int base;
            if (i4 < 262144)      { src = cur;   base = 0; }
            else if (i4 < 524288) { src = histf; base = 262144; }
            else if (i4 < 540672) { src = Wq;    base = 524288; }
            else if (i4 < 557056) { src = Wk;    base = 540672; }
            else if (i4 < 573440) { src = Wv;    base = 557056; }
            else                  { src = Wo;    base = 573440; }
            float4 v = ((const float4*)src)[i4 - base];
            half4v h;
            h[0] = (_Float16)v.x; h[1] = (_Float16)v.y;
            h[2] = (_Float16)v.z; h[3] = (_Float16)v.w;
            ((half4v*)dst)[i4] = h;
        }
    } else {
        // ---- single-block counting sort of queries by morton cell.
        // Output: order[] is a permutation of [0,NQ) grouped by cell, so
        // contiguous ranges of sorted queries are spatially compact and
        // share most of their KV neighbor rows.
        __shared__ int hcell[64];
        __shared__ int hoff[64];
        const int t = threadIdx.x;
        if (t < 64) hcell[t] = 0;
        __syncthreads();
        for (int q = t; q < NQ; q += 256) {
            int c = cell_id(qc[q * 3 + 0], qc[q * 3 + 1], qc[q * 3 + 2]);
            atomicAdd(&hcell[c], 1);
        }
        __syncthreads();
        if (t == 0) {
            int s = 0;
#pragma unroll
            for (int i = 0; i < 64; ++i) { hoff[i] = s; s += hcell[i]; }
        }
        __syncthreads();
        for (int q = t; q < NQ; q += 256) {
            int c = cell_id(qc[q * 3 + 0], qc[q * 3 + 1], qc[q * 3 + 2]);
            int pos = atomicAdd(&hoff[c], 1);
            order[pos] = (ushort_t)q;  // any within-cell order is valid
        }
    }
}

// ---------------------------------------------------------------------------
// MFMA GEMM core: C[m][n] = sum_k A[m][k] * W[n][k]  (f16 row-major, K=256).
// Wave tile 16x64, no LDS. A-frag A[m=lane&15][k=quad*8+j]; B-frag = 8
// contiguous f16 of a W row. C/D: row=quad*4+r, col=lane&15.
// ---------------------------------------------------------------------------
__device__ __forceinline__ void mfma_tile_16x64(const _Float16* __restrict__ A,
                                                const _Float16* __restrict__ W,
                                                int m0, int n0, int wave, int lane,
                                                f32x4 acc[4]) {
    const int row  = lane & 15;
    const int quad = lane >> 4;
    const _Float16* aptr = A + (size_t)(m0 + wave * 16 + row) * 256 + quad * 8;
    const _Float16* wptr = W + (size_t)(n0 + row) * 256 + quad * 8;
#pragma unroll
    for (int i = 0; i < 4; ++i) acc[i] = (f32x4){0.f, 0.f, 0.f, 0.f};
#pragma unroll
    for (int k0 = 0; k0 < 8; ++k0) {
        half8 a = *(const half8*)(aptr + k0 * 32);
#pragma unroll
        for (int nt = 0; nt < 4; ++nt) {
            half8 b = *(const half8*)(wptr + (size_t)nt * 16 * 256 + k0 * 32);
            acc[nt] = __builtin_amdgcn_mfma_f32_16x16x32_f16(a, b, acc[nt], 0, 0, 0);
        }
    }
}

// Fused QKV. z=0: Q f16 out (row-major [q][256]). z=1/2: K/V f16 into
// row-major interleaved KV[k][0:256]=K, KV[k][256:512]=V.
__global__ __launch_bounds__(256) void qkv_mfma(const _Float16* __restrict__ cb,
                                                const float* __restrict__ bq,
                                                const float* __restrict__ bk,
                                                const float* __restrict__ bv,
                                                _Float16* __restrict__ Qh,
                                                _Float16* __restrict__ KV) {
    const int z    = blockIdx.z;
    const int wave = threadIdx.x >> 6;
    const int lane = threadIdx.x & 63;
    const int m0   = blockIdx.y * 64;
    const int n0   = blockIdx.x * 64;

    const _Float16* A = (z == 0) ? (cb + CB_CUR) : (cb + CB_HIST);
    const _Float16* W = (z == 0) ? (cb + CB_WQ) : (z == 1) ? (cb + CB_WK) : (cb + CB_WV);
    const float* bias = (z == 0) ? bq : (z == 1) ? bk : bv;

    f32x4 acc[4];
    mfma_tile_16x64(A, W, m0, n0, wave, lane, acc);

    const int col  = lane & 15;
    const int quad = lane >> 4;
    float bs[4];
#pragma unroll
    for (int nt = 0; nt < 4; ++nt) bs[nt] = bias[n0 + nt * 16 + col];

    if (z == 0) {
#pragma unroll
        for (int nt = 0; nt < 4; ++nt)
#pragma unroll
            for (int r = 0; r < 4; ++r)
                Qh[(size_t)(m0 + wave * 16 + quad * 4 + r) * 256 + n0 + nt * 16 + col] =
                    (_Float16)(acc[nt][r] + bs[nt]);
    } else {
        const int off = (z == 1) ? 0 : 256;
#pragma unroll
        for (int nt = 0; nt < 4; ++nt)
#pragma unroll
            for (int r = 0; r < 4; ++r)
                KV[(size_t)(m0 + wave * 16 + quad * 4 + r) * 512 + off + n0 + nt * 16 + col] =
                    (_Float16)(acc[nt][r] + bs[nt]);
    }
}

// O-projection: out fp32 = Ob_f16 * Wo_f16^T + bo
__global__ __launch_bounds__(256) void o_mfma(const _Float16* __restrict__ Ob,
                                              const _Float16* __restrict__ Wo,
                                              const float* __restrict__ bo,
                                              float* __restrict__ out) {
    const int wave = threadIdx.x >> 6;
    const int lane = threadIdx.x & 63;
    const int m0   = blockIdx.y * 64;
    const int n0   = blockIdx.x * 64;

    f32x4 acc[4];
    mfma_tile_16x64(Ob, Wo, m0, n0, wave, lane, acc);

    const int col  = lane & 15;
    const int quad = lane >> 4;
#pragma unroll
    for (int nt = 0; nt < 4; ++nt) {
        const float b = bo[n0 + nt * 16 + col];
#pragma unroll
        for (int r = 0; r < 4; ++r)
            out[(size_t)(m0 + wave * 16 + quad * 4 + r) * 256 + n0 + nt * 16 + col] =
                acc[nt][r] + b;
    }
}

// ---------------------------------------------------------------------------
// Sparse attention v10 = v9 + KV L2-residency package:
//  * blocks process queries in spatially-sorted (morton-cell) order, and the
//    XCD-chunked swizzle widx=(b&7)*512+b/8 gives each XCD one contiguous
//    spatial slab -> its working KV set (~(8+6)^3 keys ~ 2.7 MB) fits the
//    4 MiB per-XCD L2 instead of thrashing to Infinity Cache;
//  * all streaming traffic (Qh row, nbr list, Ob store) is non-temporal so
//    it cannot evict the now-resident KV lines.
// Math per key unchanged from v9 (no max-tracking, shift-invariant softmax).
// ---------------------------------------------------------------------------
__global__ __launch_bounds__(256) void sparse_attn10(const _Float16* __restrict__ Qh,
                                                     const _Float16* __restrict__ KV,
                                                     const ushort_t* __restrict__ nbr,
                                                     const int* __restrict__ cnt,
                                                     const ushort_t* __restrict__ order,
                                                     _Float16* __restrict__ Ob) {
    __shared__ float sm[4][32][12];
    const int b    = blockIdx.x;
    // bijective XCD swizzle (4096 % 8 == 0): XCD x gets sorted range [x*512,(x+1)*512)
    const int widx = ((b & 7) << 9) | (b >> 3);
    const int q    = (int)order[widx];
    const int t    = threadIdx.x;
    const int wave = t >> 6;
    const int lane = t & 63;
    const int p    = lane >> 5;
    const int h    = (lane >> 2) & 7;
    const int s    = lane & 3;

    // 8-dim q slice for (h,s), f16 -> fp32, pre-scaled by 1/sqrt(HD)
    float qv[8];
    {
        half8 qh = nt_load_half8(Qh + (size_t)q * FDIM + h * HD + s * 8);
        const float sc = 0.17677669529663687f;
#pragma unroll
        for (int i = 0; i < 8; ++i) qv[i] = (float)qh[i] * sc;
    }

    float o[8];
#pragma unroll
    for (int i = 0; i < 8; ++i) o[i] = 0.f;
    float l = 0.f;

    const int n = cnt[q];
    const ushort_t* nl = nbr + (size_t)q * CAP;
    const int koff = h * HD + s * 8;

    for (int j = 2 * wave + p; j < n; j += 8) {
        const int k = (int)__builtin_nontemporal_load(nl + j);
        const _Float16* r = KV + ((size_t)k << 9) + koff;
        half8 k8 = *(const half8*)(r);        // KV stays temporal: want L2 hits
        half8 v8 = *(const half8*)(r + 256);

        float part = 0.f;
#pragma unroll
        for (int i = 0; i < 8; ++i)
            part = fmaf(qv[i], (float)k8[i], part);
        // full 32-dim score: reduce across the 4 s-lanes of this head
        part += __shfl_xor(part, 1, 64);
        part += __shfl_xor(part, 2, 64);

        const float pw = __expf(part);
        l += pw;
#pragma unroll
        for (int i = 0; i < 8; ++i)
            o[i] = fmaf(pw, (float)v8[i], o[i]);
    }

    // merge the two 32-lane halves (plain sums)
    l += __shfl_xor(l, 32, 64);
#pragma unroll
    for (int i = 0; i < 8; ++i) o[i] += __shfl_xor(o[i], 32, 64);

    if (lane < 32) {  // lane == h*4+s
        float* dst = &sm[wave][lane][0];
        *(float4*)(dst)     = (float4){o[0], o[1], o[2], o[3]};
        *(float4*)(dst + 4) = (float4){o[4], o[5], o[6], o[7]};
        dst[8] = l;
    }
    __syncthreads();

    if (t < 32) {  // t == h*4+s ; output offset = 8*t
        float4 x0 = *(const float4*)&sm[0][t][0];
        float4 x1 = *(const float4*)&sm[0][t][4];
        float O[8] = {x0.x, x0.y, x0.z, x0.w, x1.x, x1.y, x1.z, x1.w};
        float L = sm[0][t][8];
#pragma unroll
        for (int w = 1; w < 4; ++w) {
            float4 y0 = *(const float4*)&sm[w][t][0];
            float4 y1 = *(const float4*)&sm[w][t][4];
            L += sm[w][t][8];
            O[0] += y0.x; O[1] += y0.y; O[2] += y0.z; O[3] += y0.w;
            O[4] += y1.x; O[5] += y1.y; O[6] += y1.z; O[7] += y1.w;
        }
        const float inv = 1.0f / L;  // n==0 -> L==0 -> inf -> NaN, matches ref
        half8 ho;
#pragma unroll
        for (int i = 0; i < 8; ++i) ho[i] = (_Float16)(O[i] * inv);
        nt_store_half8(Ob + (size_t)q * FDIM + t * 8, ho);
    }
}

// ---------------------------------------------------------------------------
extern "C" void kernel_launch(void* const* d_in, const int* in_sizes, int n_in,
                              void* d_out, int out_size, void* d_ws, size_t ws_size,
                              hipStream_t stream) {
    const float* cur_feats   = (const float*)d_in[0];
    const float* hist_feats  = (const float*)d_in[1];
    const float* cur_coords  = (const float*)d_in[2];
    const float* hist_coords = (const float*)d_in[3];
    const float* bq = (const float*)d_in[5];
    const float* bk = (const float*)d_in[7];
    const float* bv = (const float*)d_in[9];
    const float* bo = (const float*)d_in[11];
    float* out = (float*)d_out;

    char* w = (char*)d_ws;
    _Float16*  Qh    = (_Float16*)(w);                      // 4096 x 256 f16 = 2 MiB
    _Float16*  KV    = (_Float16*)(w + (4 << 20));          // 4096 x 512 f16 = 4 MiB
    ushort_t*  nbr   = (ushort_t*)(w + (8 << 20));          // 4 MiB
    int*       cnt   = (int*)(w + (12 << 20));              // 16 KiB
    ushort_t*  order = (ushort_t*)(w + (12 << 20) + (32 << 10));  // 8 KiB
    _Float16*  Ob    = (_Float16*)(w + (12 << 20) + (64 << 10));  // 2 MiB
    _Float16*  cb    = (_Float16*)(w + (15 << 20));         // cast buffer ~4.5 MiB

    prep<<<2049, 256, 0, stream>>>(cur_feats, hist_feats,
                                   (const float*)d_in[4], (const float*)d_in[6],
                                   (const float*)d_in[8], (const float*)d_in[10], cb,
                                   cur_coords, hist_coords, nbr, cnt, order);

    qkv_mfma<<<dim3(4, 64, 3), 256, 0, stream>>>(cb, bq, bk, bv, Qh, KV);

    sparse_attn10<<<NQ, 256, 0, stream>>>(Qh, KV, nbr, cnt, order, Ob);

    o_mfma<<<dim3(4, 64), 256, 0, stream>>>(Ob, cb + CB_WO, bo, out);
}